// Round 3
// baseline (776.447 us; speedup 1.0000x reference)
//
#include <hip/hip_runtime.h>
#include <hip/hip_bf16.h>

#define NROWS 1000000
#define DIM 128
#define NSEG 16384
#define TILE_M 32
#define NT (NROWS / TILE_M)      // 31250 tiles
#define XH_STRIDE 136            // bf16 elems per row (128 + 8 pad; 2-way bank alias = free)
#define GRID1 768                // 256 CU x 3 blocks resident (launch_bounds 256,3)
#define EPSV 1e-5f

typedef __bf16 bf16x8 __attribute__((ext_vector_type(8)));
typedef __bf16 bf16x4 __attribute__((ext_vector_type(4)));
typedef float  f32x4  __attribute__((ext_vector_type(4)));

// Depth-2 software pipeline on the x reads: tile k's data is loaded 2 rounds
// before it is staged, so each block keeps 32 KB of global loads in flight at
// all times (96 KB/CU at 3 blocks/CU) instead of one bursty 16 KB load per
// round. Two barriers per round (B0: xh+ibuf staged; B1: stat2 visible) —
// hazard analysis unchanged from R2 (all xh/ibuf reads are pre-B1; all
// (k+1)-writes are post-B1(k)).
__global__ __launch_bounds__(256, 3)
void fused_lin_ln_scatter(const float* __restrict__ x,
                          const int*   __restrict__ batch,
                          const float* __restrict__ W,
                          const float* __restrict__ bias,
                          const float* __restrict__ lnw,
                          const float* __restrict__ lnb,
                          float* __restrict__ out) {
    __shared__ __align__(16) __bf16 xh[TILE_M * XH_STRIDE];
    __shared__ float2 stat2[2][TILE_M];
    __shared__ int    ibuf[TILE_M];

    const int t    = threadIdx.x;
    const int wave = t >> 6;
    const int lane = t & 63;
    const int q    = lane >> 4;     // quad within wave
    const int l15  = lane & 15;
    const int rg   = wave >> 1;     // row group (0/1): rows rg*16..+16
    const int fh   = wave & 1;      // feature half (0/1)
    const int fbase = fh * 64;

    // ---- W fragments to registers (single bf16 pass; 64 VGPRs), once per block ----
    bf16x8 whf[4][4];
    #pragma unroll
    for (int nt = 0; nt < 4; ++nt) {
        const int f = fbase + nt * 16 + l15;
        #pragma unroll
        for (int ks = 0; ks < 4; ++ks) {
            const int k0 = ks * 32 + q * 8;
            const float4* wp = (const float4*)(W + f * DIM + k0);
            float4 a = wp[0], c = wp[1];
            float wv[8] = {a.x, a.y, a.z, a.w, c.x, c.y, c.z, c.w};
            bf16x8 hi;
            #pragma unroll
            for (int j = 0; j < 8; ++j) hi[j] = (__bf16)wv[j];
            whf[nt][ks] = hi;
        }
    }
    float bb[4], lwv[4], lbv[4];
    #pragma unroll
    for (int nt = 0; nt < 4; ++nt) {
        const int f = fbase + nt * 16 + l15;
        bb[nt]  = bias[f];
        lwv[nt] = lnw[f];
        lbv[nt] = lnb[f];
    }

    // ---- prologue: prefetch TWO tiles into registers ----
    // blockIdx < 768, so it0 and it0+GRID1 are both < NT always.
    float4 xr[2][4];
    int    ibv[2];
    {
        const int it0 = blockIdx.x;
        #pragma unroll
        for (int h = 0; h < 2; ++h) {
            const float4* xp = (const float4*)(x + (size_t)(it0 + h * GRID1) * TILE_M * DIM);
            #pragma unroll
            for (int j = 0; j < 4; ++j) xr[h][j] = xp[t + 256 * j];
        }
        if (t < TILE_M) {
            ibv[0] = batch[it0 * TILE_M + t];
            ibv[1] = batch[(it0 + GRID1) * TILE_M + t];
        }
    }

    for (int it = blockIdx.x; it < NT; it += 2 * GRID1) {
        #pragma unroll
        for (int h = 0; h < 2; ++h) {
            const int itc = it + h * GRID1;
            if (itc >= NT) break;                 // block-uniform

            // 1: stage tile itc (regs xr[h] -> bf16 LDS) + segment ids
            #pragma unroll
            for (int j = 0; j < 4; ++j) {
                const int idx = t + 256 * j;
                const int row = idx >> 5;
                const int c4  = (idx & 31) * 4;
                float4 v = xr[h][j];
                bf16x4 pk = {(__bf16)v.x, (__bf16)v.y, (__bf16)v.z, (__bf16)v.w};
                *(bf16x4*)&xh[row * XH_STRIDE + c4] = pk;
            }
            if (t < TILE_M) ibuf[t] = ibv[h];
            __syncthreads();   // B0

            // 2: snapshot this wave's segment ids into registers
            const int s_first = ibuf[rg * 16];
            const int s_last  = ibuf[rg * 16 + 15];
            int sgr[4];
            #pragma unroll
            for (int r = 0; r < 4; ++r) sgr[r] = ibuf[rg * 16 + q * 4 + r];

            // 3: prefetch tile itc + 2*GRID1 into xr[h] (consumed 2 rounds later)
            const int itn = itc + 2 * GRID1;
            if (itn < NT) {
                const float4* xp = (const float4*)(x + (size_t)itn * TILE_M * DIM);
                #pragma unroll
                for (int j = 0; j < 4; ++j) xr[h][j] = xp[t + 256 * j];
                if (t < TILE_M) ibv[h] = batch[itn * TILE_M + t];
            }

            // 4: MFMA — 16 rows x 64 feats per wave, K=128, bias folded into acc
            f32x4 acc[4];
            #pragma unroll
            for (int nt = 0; nt < 4; ++nt)
                acc[nt] = (f32x4){bb[nt], bb[nt], bb[nt], bb[nt]};
            const int row_l = rg * 16 + l15;
            #pragma unroll
            for (int ks = 0; ks < 4; ++ks) {
                bf16x8 af = *(const bf16x8*)&xh[row_l * XH_STRIDE + ks * 32 + q * 8];
                #pragma unroll
                for (int nt = 0; nt < 4; ++nt)
                    acc[nt] = __builtin_amdgcn_mfma_f32_16x16x32_bf16(af, whf[nt][ks], acc[nt], 0, 0, 0);
            }

            // 5: row stats over this wave's 64 features (16-lane butterfly)
            #pragma unroll
            for (int r = 0; r < 4; ++r) {
                float s  = acc[0][r] + acc[1][r] + acc[2][r] + acc[3][r];
                float sq = acc[0][r] * acc[0][r] + acc[1][r] * acc[1][r]
                         + acc[2][r] * acc[2][r] + acc[3][r] * acc[3][r];
                #pragma unroll
                for (int m = 1; m < 16; m <<= 1) {
                    s  += __shfl_xor(s,  m, 64);
                    sq += __shfl_xor(sq, m, 64);
                }
                if (l15 == 0)
                    stat2[fh][rg * 16 + q * 4 + r] = make_float2(s, sq);
            }
            __syncthreads();   // B1

            // 6: normalize in registers
            float nv[4][4];
            #pragma unroll
            for (int r = 0; r < 4; ++r) {
                const int row = rg * 16 + q * 4 + r;
                float2 u0 = stat2[0][row], u1 = stat2[1][row];
                float mean = (u0.x + u1.x) * (1.0f / 128.0f);
                float var  = (u0.y + u1.y) * (1.0f / 128.0f) - mean * mean;
                float rs   = rsqrtf(var + EPSV);
                #pragma unroll
                for (int nt = 0; nt < 4; ++nt)
                    nv[nt][r] = (acc[nt][r] - mean) * rs * lwv[nt] + lbv[nt];
            }

            // 7: segmented scatter from registers
            if (s_first == s_last) {
                #pragma unroll
                for (int nt = 0; nt < 4; ++nt) {
                    float v = nv[nt][0] + nv[nt][1] + nv[nt][2] + nv[nt][3];
                    v += __shfl_xor(v, 16, 64);
                    v += __shfl_xor(v, 32, 64);
                    if (q == 0)
                        atomicAdd(out + (size_t)s_first * DIM + fbase + nt * 16 + l15, v);
                }
            } else {
                #pragma unroll
                for (int nt = 0; nt < 4; ++nt) {
                    const int f = fbase + nt * 16 + l15;
                    float a = nv[nt][0];
                    #pragma unroll
                    for (int r = 1; r < 4; ++r) {
                        if (sgr[r] != sgr[r - 1]) {
                            atomicAdd(out + (size_t)sgr[r - 1] * DIM + f, a);
                            a = 0.f;
                        }
                        a += nv[nt][r];
                    }
                    atomicAdd(out + (size_t)sgr[3] * DIM + f, a);
                }
            }
            // no trailing barrier (safe per hazard analysis above)
        }
    }
}

__device__ __forceinline__ int lower_bound_seg(const int* __restrict__ batch, int v) {
    int lo = 0, hi = NROWS;
    while (lo < hi) {
        int m = (lo + hi) >> 1;
        if (batch[m] < v) lo = m + 1; else hi = m;
    }
    return lo;
}

// 128 blocks x 256 threads; block handles 128 segments. 129 parallel binary
// searches -> reciprocal counts in LDS -> coalesced scale of 16384 floats.
#define SEGS_PER_BLK 128
__global__ __launch_bounds__(256)
void finalize_divide(float* __restrict__ out, const int* __restrict__ batch) {
    __shared__ int   bnd[SEGS_PER_BLK + 1];
    __shared__ float rinv[SEGS_PER_BLK];
    const int t  = threadIdx.x;
    const int s0 = blockIdx.x * SEGS_PER_BLK;
    if (t <= SEGS_PER_BLK) bnd[t] = lower_bound_seg(batch, s0 + t);
    __syncthreads();
    if (t < SEGS_PER_BLK) {
        const int c = bnd[t + 1] - bnd[t];
        rinv[t] = 1.0f / (float)max(c, 1);
    }
    __syncthreads();
    float* base = out + (size_t)s0 * DIM;
    #pragma unroll
    for (int i = 0; i < (SEGS_PER_BLK * DIM) / 256; ++i) {
        const int idx = t + 256 * i;
        base[idx] *= rinv[idx >> 7];
    }
}

extern "C" void kernel_launch(void* const* d_in, const int* in_sizes, int n_in,
                              void* d_out, int out_size, void* d_ws, size_t ws_size,
                              hipStream_t stream) {
    const float* x     = (const float*)d_in[0];
    const int*   batch = (const int*)d_in[1];
    const float* W     = (const float*)d_in[2];
    const float* bias  = (const float*)d_in[3];
    const float* lnw   = (const float*)d_in[4];
    const float* lnb   = (const float*)d_in[5];
    float* out = (float*)d_out;

    hipMemsetAsync(out, 0, (size_t)out_size * sizeof(float), stream);
    fused_lin_ln_scatter<<<GRID1, 256, 0, stream>>>(x, batch, W, bias, lnw, lnb, out);
    finalize_divide<<<NSEG / SEGS_PER_BLK, 256, 0, stream>>>(out, batch);
}